// Round 10
// baseline (290.921 us; speedup 1.0000x reference)
//
#include <hip/hip_runtime.h>
#include <stdint.h>

// ---------------------------------------------------------------------------
// CausalSelfAttention (B=4, T=2048, C=1024, H=16, D=64) on gfx950.
// cast x->bf16; transpose W's to [N][K] bf16; QKV GEMM (256x256 tile, 8-wave,
// k-half-phased counted-vmcnt schedule, swizzled LDS) writing Q*0.125*log2e,
// K, V^T; causal flash attention (32x32 swapped-QK^T); proj GEMM (same core).
// ---------------------------------------------------------------------------

typedef __attribute__((ext_vector_type(8))) __bf16 bf16x8_t;   // MFMA A/B frag
typedef __attribute__((ext_vector_type(4))) float f32x4_t;     // 16x16 C/D
typedef __attribute__((ext_vector_type(16))) float f32x16_t;   // 32x32 C/D
typedef __attribute__((ext_vector_type(4))) unsigned short u16x4_t;
typedef __attribute__((ext_vector_type(4))) unsigned int u32x4_t;

static __device__ __forceinline__ unsigned short f2bf(float f) {
  union { float f; unsigned u; } c; c.f = f;
  unsigned r = c.u + 0x7FFFu + ((c.u >> 16) & 1u);  // RNE
  return (unsigned short)(r >> 16);
}

static __device__ __forceinline__ unsigned cvt_pk_bf16(float lo, float hi) {
  unsigned r;
  asm volatile("v_cvt_pk_bf16_f32 %0, %1, %2" : "=v"(r) : "v"(lo), "v"(hi));
  return r;
}

// v_permlane32_swap_b32 a,b : a.hi32lanes <-> b.lo32lanes (both updated)
static __device__ __forceinline__ void perm32swap(unsigned& a, unsigned& b) {
  asm volatile("v_permlane32_swap_b32 %0, %1" : "+v"(a), "+v"(b));
}

static __device__ __forceinline__ f32x16_t zero16() {
  f32x16_t v;
#pragma unroll
  for (int i = 0; i < 16; ++i) v[i] = 0.f;
  return v;
}

// async global->LDS, 16B per lane. LDS dest must be (wave-uniform base +
// lane*16) linear; global src IS per-lane (m173) -> swizzle the source.
static __device__ __forceinline__ void gload16(const void* g, void* lds) {
  __builtin_amdgcn_global_load_lds(
      (const __attribute__((address_space(1))) unsigned int*)g,
      (__attribute__((address_space(3))) unsigned int*)(uint32_t)(uintptr_t)lds,
      16, 0, 0);
}

// ---------------------------------------------------------------------------
__global__ __launch_bounds__(256) void k_cast_bf16(const float* __restrict__ in,
                                                   unsigned short* __restrict__ out) {
  int i = blockIdx.x * 256 + threadIdx.x;
  float4 v = ((const float4*)in)[i];
  u16x4_t r = { f2bf(v.x), f2bf(v.y), f2bf(v.z), f2bf(v.w) };
  ((u16x4_t*)out)[i] = r;
}

__global__ __launch_bounds__(256) void k_transpose_cast(const float* __restrict__ W,
                                                        unsigned short* __restrict__ Wt,
                                                        int Kd, int Nd) {
  __shared__ float tile[32][33];
  int n0 = blockIdx.x * 32, k0 = blockIdx.y * 32;
  int tx = threadIdx.x, ty = threadIdx.y;
#pragma unroll
  for (int i = 0; i < 4; ++i)
    tile[ty + 8 * i][tx] = W[(size_t)(k0 + ty + 8 * i) * Nd + n0 + tx];
  __syncthreads();
#pragma unroll
  for (int i = 0; i < 4; ++i)
    Wt[(size_t)(n0 + ty + 8 * i) * Kd + k0 + tx] = f2bf(tile[tx][ty + 8 * i]);
}

// ---------------------------------------------------------------------------
// 256x256 GEMM core, BK=64 split in 2 k-half phases. 8 waves (2m x 4n),
// per-wave C = 128x64 (8x4 16x16x32 frags, acc 128 VGPR).
// LDS: [slot][k-half][256 rows][32 u16] per operand = 64KB A + 64KB B.
// In-half swizzle: physical chunk = logical ^ ((row>>1)&3)  (involution,
// applied on stage source AND read; keeps gload dest linear; read pattern is
// uniform 2-lanes-per-granule = free per m136).
// Phase (T,h): vmcnt(4) -> s_barrier -> STAGE(T+1,h -> slot^1) ->
//              12 ds_read -> setprio(1) 32 MFMA setprio(0).
// vmcnt(4) derivation: at each gate exactly one newer STAGE (4 loads) is in
// flight; everything older (incl. the needed half) has landed. Tail: clamped
// re-stage keeps the count uniform (writes target a dead slot).
static __device__ __forceinline__ void gemm_core(
    const unsigned short* __restrict__ A, const unsigned short* __restrict__ Bt,
    int Kd, int bm0, int bn0,
    unsigned short (*As)[8192], unsigned short (*Bs)[8192],  // [slot*2+half]
    f32x4_t acc[8][4]) {
  const int tid = threadIdx.x;
  const int lane = tid & 63;
  const int wid = tid >> 6;
  const int wm = wid >> 2, wn = wid & 3;
  const int l15 = lane & 15, lhi = (lane >> 4) & 3;
  const int r0 = tid >> 2;                 // staging row 0..127 (+128)
  const int cd = tid & 3;                  // staging dest chunk
  const int NK = Kd >> 6;

  auto STAGE = [&](int kt, int h, int sl) {
#pragma unroll
    for (int j = 0; j < 2; ++j) {
      const int row = r0 + 128 * j;
      const int sc = cd ^ ((row >> 1) & 3);          // source chunk (inverse swz)
      gload16(A + (size_t)(bm0 + row) * Kd + kt * 64 + h * 32 + sc * 8,
              &As[sl * 2 + h][row * 32 + cd * 8]);
    }
#pragma unroll
    for (int j = 0; j < 2; ++j) {
      const int row = r0 + 128 * j;
      const int sc = cd ^ ((row >> 1) & 3);
      gload16(Bt + (size_t)(bn0 + row) * Kd + kt * 64 + h * 32 + sc * 8,
              &Bs[sl * 2 + h][row * 32 + cd * 8]);
    }
  };

  STAGE(0, 0, 0);
  STAGE(0, 1, 0);
  for (int kt = 0; kt < NK; ++kt) {
    const int sl = kt & 1;
    const int ktn = (kt + 1 < NK) ? kt + 1 : kt;     // tail clamp (dead slot)
#pragma unroll
    for (int h = 0; h < 2; ++h) {
      asm volatile("s_waitcnt vmcnt(4)" ::: "memory");
      __builtin_amdgcn_sched_barrier(0);
      __builtin_amdgcn_s_barrier();
      __builtin_amdgcn_sched_barrier(0);
      STAGE(ktn, h, sl ^ 1);
      bf16x8_t af[8], bfr[4];
#pragma unroll
      for (int m = 0; m < 8; ++m) {
        const int ar = wm * 128 + m * 16 + l15;
        af[m] = *(const bf16x8_t*)&As[sl * 2 + h][ar * 32 + ((lhi ^ ((ar >> 1) & 3)) << 3)];
      }
#pragma unroll
      for (int n = 0; n < 4; ++n) {
        const int br = wn * 64 + n * 16 + l15;
        bfr[n] = *(const bf16x8_t*)&Bs[sl * 2 + h][br * 32 + ((lhi ^ ((br >> 1) & 3)) << 3)];
      }
      __builtin_amdgcn_s_setprio(1);
#pragma unroll
      for (int m = 0; m < 8; ++m)
#pragma unroll
        for (int n = 0; n < 4; ++n)
          acc[m][n] = __builtin_amdgcn_mfma_f32_16x16x32_bf16(af[m], bfr[n], acc[m][n], 0, 0, 0);
      __builtin_amdgcn_s_setprio(0);
    }
  }
}

// QKV GEMM. Q scaled by 0.125*log2(e), V transposed. grid 384 = 32 x 12.
__global__ __launch_bounds__(512, 2) void k_gemm_qkv(
    const unsigned short* __restrict__ A, const unsigned short* __restrict__ Bt,
    const float* __restrict__ bias,
    unsigned short* __restrict__ Qo, unsigned short* __restrict__ Ko,
    unsigned short* __restrict__ Vo) {
  __shared__ alignas(16) unsigned short As[4][8192];
  __shared__ alignas(16) unsigned short Bs[4][8192];
  const int orig = blockIdx.x;
  const int swz = (orig & 7) * 48 + (orig >> 3);   // 384/8 = 48, bijective
  const int by = swz / 12, bx = swz % 12;
  f32x4_t acc[8][4];
  f32x4_t z = {0.f, 0.f, 0.f, 0.f};
#pragma unroll
  for (int m = 0; m < 8; ++m)
#pragma unroll
    for (int n = 0; n < 4; ++n) acc[m][n] = z;
  gemm_core(A, Bt, 1024, by * 256, bx * 256, As, Bs, acc);
  const int tid = threadIdx.x, lane = tid & 63;
  const int wid = tid >> 6, wm = wid >> 2, wn = wid & 3;
  const int l15 = lane & 15, lhi = (lane >> 4) & 3;
#pragma unroll
  for (int n = 0; n < 4; ++n) {
    int col = bx * 256 + wn * 64 + n * 16 + l15;
    int which = col >> 10;                 // 0=q 1=k 2=v
    int h = (col >> 6) & 15;
    int d = col & 63;
    float bv = bias[col];
#pragma unroll
    for (int m = 0; m < 8; ++m)
#pragma unroll
      for (int r = 0; r < 4; ++r) {
        int row = by * 256 + wm * 128 + m * 16 + lhi * 4 + r;
        int b = row >> 11, t = row & 2047;
        float val = acc[m][n][r] + bv;
        if (which == 0)
          Qo[(size_t)((b * 16 + h) * 2048 + t) * 64 + d] = f2bf(val * 0.18033688011112042f);
        else if (which == 1)
          Ko[(size_t)((b * 16 + h) * 2048 + t) * 64 + d] = f2bf(val);
        else
          Vo[(size_t)((b * 16 + h) * 64 + d) * 2048 + t] = f2bf(val);
      }
  }
}

// proj GEMM: out fp32 [8192][1024]. grid 128 = 32 x 4.
__global__ __launch_bounds__(512, 2) void k_gemm_proj(
    const unsigned short* __restrict__ A, const unsigned short* __restrict__ Bt,
    const float* __restrict__ bias, float* __restrict__ out) {
  __shared__ alignas(16) unsigned short As[4][8192];
  __shared__ alignas(16) unsigned short Bs[4][8192];
  const int orig = blockIdx.x;
  const int swz = (orig & 7) * 16 + (orig >> 3);   // 128/8 = 16, bijective
  const int by = swz >> 2, bx = swz & 3;
  f32x4_t acc[8][4];
  f32x4_t z = {0.f, 0.f, 0.f, 0.f};
#pragma unroll
  for (int m = 0; m < 8; ++m)
#pragma unroll
    for (int n = 0; n < 4; ++n) acc[m][n] = z;
  gemm_core(A, Bt, 1024, by * 256, bx * 256, As, Bs, acc);
  const int tid = threadIdx.x, lane = tid & 63;
  const int wid = tid >> 6, wm = wid >> 2, wn = wid & 3;
  const int l15 = lane & 15, lhi = (lane >> 4) & 3;
#pragma unroll
  for (int n = 0; n < 4; ++n) {
    int col = bx * 256 + wn * 64 + n * 16 + l15;
    float bv = bias[col];
#pragma unroll
    for (int m = 0; m < 8; ++m)
#pragma unroll
      for (int r = 0; r < 4; ++r) {
        int row = by * 256 + wm * 128 + m * 16 + lhi * 4 + r;
        out[(size_t)row * 1024 + col] = acc[m][n][r] + bv;
      }
  }
}

// ---------------------------------------------------------------------------
// causal flash attention, 32x32 swapped structure (T12) — unchanged from R7.
__global__ __launch_bounds__(256) void k_attn(const unsigned short* __restrict__ Q,
                                              const unsigned short* __restrict__ K,
                                              const unsigned short* __restrict__ Vt,
                                              unsigned short* __restrict__ O) {
  __shared__ alignas(16) unsigned short KT[2][4096];  // [kv 64][d 64] swizzled
  __shared__ alignas(16) unsigned short VT[2][4096];  // [d 64][kv 64] swizzled
  const int flat = blockIdx.x;
  const int bx = 15 - (flat >> 6);       // heavy diagonal blocks first
  const int bh = flat & 63;              // same bh -> same XCD (64 % 8 == 0)
  const int tid = threadIdx.x;
  const int lane = tid & 63;
  const int w = tid >> 6;
  const int l31 = lane & 31;
  const int hi = lane >> 5;
  const int sw = l31 & 7;                // read-side XOR chunk (row&7)
  const unsigned short* Qh = Q + (size_t)bh * 2048 * 64;
  const unsigned short* Kh = K + (size_t)bh * 2048 * 64;
  const unsigned short* Vh = Vt + (size_t)bh * 64 * 2048;
  const int qrow = bx * 128 + w * 32;    // wave q-base
  const int qg = qrow + l31;             // lane's q row
  const int NT = 2 * bx + 2;             // kv tiles staged by this block

  bf16x8_t qf[4];
#pragma unroll
  for (int s = 0; s < 4; ++s)
    qf[s] = *(const bf16x8_t*)&Qh[(size_t)qg * 64 + s * 16 + hi * 8];

  f32x16_t ot0 = zero16(), ot1 = zero16();  // O^T: d-tiles 0/1, col=q=l31
  float m_r = -1e30f, l_r = 0.f;

  const int srow = tid >> 3;             // staging row 0..31 (+32 second half)
  const int ssw = 8 * ((tid & 7) ^ (srow & 7));  // source-side XOR (u16)
  auto STAGE = [&](int t_, int buf_) {
#pragma unroll
    for (int i = 0; i < 2; ++i) {
      const int r_ = i * 32 + srow;
      gload16(Kh + (size_t)(t_ * 64 + r_) * 64 + ssw, &KT[buf_][i * 2048 + tid * 8]);
      gload16(Vh + (size_t)r_ * 2048 + t_ * 64 + ssw, &VT[buf_][i * 2048 + tid * 8]);
    }
  };

  STAGE(0, 0);
  __syncthreads();
  for (int t = 0; t < NT; ++t) {
    const int buf = t & 1;
    if (t + 1 < NT) STAGE(t + 1, buf ^ 1);
    if (t * 64 <= qrow + 31) {           // wave-uniform: tile intersects causal range
      f32x16_t st[2];
#pragma unroll
      for (int tt = 0; tt < 2; ++tt) {
        st[tt] = zero16();
        const unsigned short* kr = &KT[buf][(tt * 32 + l31) * 64];
#pragma unroll
        for (int s = 0; s < 4; ++s) {
          bf16x8_t kf = *(const bf16x8_t*)&kr[((2 * s + hi) ^ sw) * 8];
          st[tt] = __builtin_amdgcn_mfma_f32_32x32x16_bf16(kf, qf[s], st[tt], 0, 0, 0);
        }
      }
      if (t * 64 + 63 > qrow) {
#pragma unroll
        for (int tt = 0; tt < 2; ++tt)
#pragma unroll
          for (int r = 0; r < 16; ++r) {
            int kv = t * 64 + tt * 32 + (r & 3) + 8 * (r >> 2) + 4 * hi;
            if (kv > qg) st[tt][r] = -1e30f;
          }
      }
      float mx = st[0][0];
#pragma unroll
      for (int tt = 0; tt < 2; ++tt)
#pragma unroll
        for (int r = 0; r < 16; ++r) mx = fmaxf(mx, st[tt][r]);
      mx = fmaxf(mx, __shfl_xor(mx, 32));
      float mnew = fmaxf(m_r, mx);
      float resc = __builtin_amdgcn_exp2f(m_r - mnew);
      float u = 0.f;
#pragma unroll
      for (int tt = 0; tt < 2; ++tt)
#pragma unroll
        for (int r = 0; r < 16; ++r) {
          float pv = __builtin_amdgcn_exp2f(st[tt][r] - mnew);
          st[tt][r] = pv;
          u += pv;
        }
      u += __shfl_xor(u, 32);
      l_r = l_r * resc + u;
      m_r = mnew;
      ot0 *= resc;
      ot1 *= resc;
#pragma unroll
      for (int tt = 0; tt < 2; ++tt) {
        unsigned W0 = cvt_pk_bf16(st[tt][0], st[tt][1]);
        unsigned W1 = cvt_pk_bf16(st[tt][2], st[tt][3]);
        unsigned W2 = cvt_pk_bf16(st[tt][4], st[tt][5]);
        unsigned W3 = cvt_pk_bf16(st[tt][6], st[tt][7]);
        unsigned W4 = cvt_pk_bf16(st[tt][8], st[tt][9]);
        unsigned W5 = cvt_pk_bf16(st[tt][10], st[tt][11]);
        unsigned W6 = cvt_pk_bf16(st[tt][12], st[tt][13]);
        unsigned W7 = cvt_pk_bf16(st[tt][14], st[tt][15]);
        perm32swap(W0, W2);
        perm32swap(W1, W3);
        perm32swap(W4, W6);
        perm32swap(W5, W7);
        u32x4_t fe = {W0, W1, W2, W3};   // kv window 32tt + [0,16)
        u32x4_t fo = {W4, W5, W6, W7};   // kv window 32tt + [16,32)
        bf16x8_t pe = __builtin_bit_cast(bf16x8_t, fe);
        bf16x8_t po = __builtin_bit_cast(bf16x8_t, fo);
        const unsigned short* vr0 = &VT[buf][l31 * 64];         // d-tile 0
        const unsigned short* vr1 = &VT[buf][(32 + l31) * 64];  // d-tile 1
        bf16x8_t ve0 = *(const bf16x8_t*)&vr0[((4 * tt + hi) ^ sw) * 8];
        bf16x8_t vo0 = *(const bf16x8_t*)&vr0[((4 * tt + 2 + hi) ^ sw) * 8];
        bf16x8_t ve1 = *(const bf16x8_t*)&vr1[((4 * tt + hi) ^ sw) * 8];
        bf16x8_t vo1 = *(const bf16x8_t*)&vr1[((4 * tt + 2 + hi) ^ sw) * 8];
        ot0 = __builtin_amdgcn_mfma_f32_32x32x16_bf16(ve0, pe, ot0, 0, 0, 0);
        ot0 = __builtin_amdgcn_mfma_f32_32x32x16_bf16(vo0, po, ot0, 0, 0, 0);
        ot1 = __builtin_amdgcn_mfma_f32_32x32x16_bf16(ve1, pe, ot1, 0, 0, 0);
        ot1 = __builtin_amdgcn_mfma_f32_32x32x16_bf16(vo1, po, ot1, 0, 0, 0);
      }
    }
    __syncthreads();
  }
  const float inv = 1.0f / l_r;
  const int b = bh >> 4, h = bh & 15;
  unsigned short* orow = O + (size_t)(b * 2048 + qg) * 1024 + h * 64;
#pragma unroll
  for (int m = 0; m < 4; ++m) {          // d = 8m + 4hi + {0..3} (+32 for ot1)
    u16x4_t r0, r1;
#pragma unroll
    for (int j = 0; j < 4; ++j) {
      r0[j] = f2bf(ot0[4 * m + j] * inv);
      r1[j] = f2bf(ot1[4 * m + j] * inv);
    }
    *(u16x4_t*)&orow[8 * m + 4 * hi] = r0;
    *(u16x4_t*)&orow[32 + 8 * m + 4 * hi] = r1;
  }
}

// ---------------------------------------------------------------------------
extern "C" void kernel_launch(void* const* d_in, const int* in_sizes, int n_in,
                              void* d_out, int out_size, void* d_ws, size_t ws_size,
                              hipStream_t stream) {
  const float* x     = (const float*)d_in[0];
  const float* Wqkv  = (const float*)d_in[1];
  const float* bqkv  = (const float*)d_in[2];
  const float* Wproj = (const float*)d_in[3];
  const float* bproj = (const float*)d_in[4];
  float* out = (float*)d_out;

  char* ws = (char*)d_ws;
  unsigned short* xb     = (unsigned short*)(ws);                    // 16 MiB
  unsigned short* wqkvT  = (unsigned short*)(ws + 16777216);         // 6 MiB
  unsigned short* wprojT = (unsigned short*)(ws + 23068672);         // 2 MiB
  unsigned short* Qb     = (unsigned short*)(ws + 25165824);         // 16 MiB (B,H,T,D) *0.125*log2e
  unsigned short* Kb     = (unsigned short*)(ws + 41943040);         // 16 MiB (B,H,T,D)
  unsigned short* Vb     = (unsigned short*)(ws + 58720256);         // 16 MiB (B,H,D,T) transposed
  unsigned short* Ob     = (unsigned short*)(ws + 75497472);         // 16 MiB (B,T,C)

  k_cast_bf16<<<8192, 256, 0, stream>>>(x, xb);
  k_transpose_cast<<<dim3(96, 32), dim3(32, 8), 0, stream>>>(Wqkv, wqkvT, 1024, 3072);
  k_transpose_cast<<<dim3(32, 32), dim3(32, 8), 0, stream>>>(Wproj, wprojT, 1024, 1024);
  k_gemm_qkv<<<384, 512, 0, stream>>>(xb, wqkvT, bqkv, Qb, Kb, Vb);
  k_attn<<<1024, 256, 0, stream>>>(Qb, Kb, Vb, Ob);
  k_gemm_proj<<<128, 512, 0, stream>>>(Ob, wprojT, bproj, out);
}

// Round 11
// 257.721 us; speedup vs baseline: 1.1288x; 1.1288x over previous
//
#include <hip/hip_runtime.h>
#include <stdint.h>

// ---------------------------------------------------------------------------
// CausalSelfAttention (B=4, T=2048, C=1024, H=16, D=64) on gfx950.
// cast x->bf16; transpose W's to [N][K] bf16; QKV GEMM (256x256 tile, 8-wave,
// k-half-phased counted-vmcnt schedule, swizzled LDS, V^T written via LDS
// transpose for coalesced stores, 2D XCD-region swizzle) writing Q*0.125*log2e,
// K, V^T; causal flash attention (32x32 swapped-QK^T); proj GEMM (same core).
// ---------------------------------------------------------------------------

typedef __attribute__((ext_vector_type(8))) __bf16 bf16x8_t;   // MFMA A/B frag
typedef __attribute__((ext_vector_type(4))) float f32x4_t;     // 16x16 C/D
typedef __attribute__((ext_vector_type(16))) float f32x16_t;   // 32x32 C/D
typedef __attribute__((ext_vector_type(4))) unsigned short u16x4_t;
typedef __attribute__((ext_vector_type(4))) unsigned int u32x4_t;

static __device__ __forceinline__ unsigned short f2bf(float f) {
  union { float f; unsigned u; } c; c.f = f;
  unsigned r = c.u + 0x7FFFu + ((c.u >> 16) & 1u);  // RNE
  return (unsigned short)(r >> 16);
}

static __device__ __forceinline__ unsigned cvt_pk_bf16(float lo, float hi) {
  unsigned r;
  asm volatile("v_cvt_pk_bf16_f32 %0, %1, %2" : "=v"(r) : "v"(lo), "v"(hi));
  return r;
}

// v_permlane32_swap_b32 a,b : a.hi32lanes <-> b.lo32lanes (both updated)
static __device__ __forceinline__ void perm32swap(unsigned& a, unsigned& b) {
  asm volatile("v_permlane32_swap_b32 %0, %1" : "+v"(a), "+v"(b));
}

static __device__ __forceinline__ f32x16_t zero16() {
  f32x16_t v;
#pragma unroll
  for (int i = 0; i < 16; ++i) v[i] = 0.f;
  return v;
}

// async global->LDS, 16B per lane. LDS dest must be (wave-uniform base +
// lane*16) linear; global src IS per-lane (m173) -> swizzle the source.
static __device__ __forceinline__ void gload16(const void* g, void* lds) {
  __builtin_amdgcn_global_load_lds(
      (const __attribute__((address_space(1))) unsigned int*)g,
      (__attribute__((address_space(3))) unsigned int*)(uint32_t)(uintptr_t)lds,
      16, 0, 0);
}

// ---------------------------------------------------------------------------
__global__ __launch_bounds__(256) void k_cast_bf16(const float* __restrict__ in,
                                                   unsigned short* __restrict__ out) {
  int i = blockIdx.x * 256 + threadIdx.x;
  float4 v = ((const float4*)in)[i];
  u16x4_t r = { f2bf(v.x), f2bf(v.y), f2bf(v.z), f2bf(v.w) };
  ((u16x4_t*)out)[i] = r;
}

__global__ __launch_bounds__(256) void k_transpose_cast(const float* __restrict__ W,
                                                        unsigned short* __restrict__ Wt,
                                                        int Kd, int Nd) {
  __shared__ float tile[32][33];
  int n0 = blockIdx.x * 32, k0 = blockIdx.y * 32;
  int tx = threadIdx.x, ty = threadIdx.y;
#pragma unroll
  for (int i = 0; i < 4; ++i)
    tile[ty + 8 * i][tx] = W[(size_t)(k0 + ty + 8 * i) * Nd + n0 + tx];
  __syncthreads();
#pragma unroll
  for (int i = 0; i < 4; ++i)
    Wt[(size_t)(n0 + ty + 8 * i) * Kd + k0 + tx] = f2bf(tile[tx][ty + 8 * i]);
}

// ---------------------------------------------------------------------------
// 256x256 GEMM core, BK=64 in 2 k-half phases (unchanged from R10 — verified
// correct, 0 bank conflicts). LDS carved from one 128 KB SH buffer:
// A slots at SH + s*8192, B slots at SH + 32768 + s*8192 (s = sl*2+half).
static __device__ __forceinline__ void gemm_core(
    const unsigned short* __restrict__ A, const unsigned short* __restrict__ Bt,
    int Kd, int bm0, int bn0, unsigned short* SH, f32x4_t acc[8][4]) {
  const int tid = threadIdx.x;
  const int lane = tid & 63;
  const int wid = tid >> 6;
  const int wm = wid >> 2, wn = wid & 3;
  const int l15 = lane & 15, lhi = (lane >> 4) & 3;
  const int r0 = tid >> 2;                 // staging row 0..127 (+128)
  const int cd = tid & 3;                  // staging dest chunk
  const int NK = Kd >> 6;

  auto STAGE = [&](int kt, int h, int sl) {
    unsigned short* Asl = SH + (sl * 2 + h) * 8192;
    unsigned short* Bsl = SH + 32768 + (sl * 2 + h) * 8192;
#pragma unroll
    for (int j = 0; j < 2; ++j) {
      const int row = r0 + 128 * j;
      const int sc = cd ^ ((row >> 1) & 3);          // source chunk (inverse swz)
      gload16(A + (size_t)(bm0 + row) * Kd + kt * 64 + h * 32 + sc * 8,
              &Asl[row * 32 + cd * 8]);
    }
#pragma unroll
    for (int j = 0; j < 2; ++j) {
      const int row = r0 + 128 * j;
      const int sc = cd ^ ((row >> 1) & 3);
      gload16(Bt + (size_t)(bn0 + row) * Kd + kt * 64 + h * 32 + sc * 8,
              &Bsl[row * 32 + cd * 8]);
    }
  };

  STAGE(0, 0, 0);
  STAGE(0, 1, 0);
  for (int kt = 0; kt < NK; ++kt) {
    const int sl = kt & 1;
    const int ktn = (kt + 1 < NK) ? kt + 1 : kt;     // tail clamp (dead slot)
#pragma unroll
    for (int h = 0; h < 2; ++h) {
      asm volatile("s_waitcnt vmcnt(4)" ::: "memory");
      __builtin_amdgcn_sched_barrier(0);
      __builtin_amdgcn_s_barrier();
      __builtin_amdgcn_sched_barrier(0);
      STAGE(ktn, h, sl ^ 1);
      const unsigned short* Asl = SH + (sl * 2 + h) * 8192;
      const unsigned short* Bsl = SH + 32768 + (sl * 2 + h) * 8192;
      bf16x8_t af[8], bfr[4];
#pragma unroll
      for (int m = 0; m < 8; ++m) {
        const int ar = wm * 128 + m * 16 + l15;
        af[m] = *(const bf16x8_t*)&Asl[ar * 32 + ((lhi ^ ((ar >> 1) & 3)) << 3)];
      }
#pragma unroll
      for (int n = 0; n < 4; ++n) {
        const int br = wn * 64 + n * 16 + l15;
        bfr[n] = *(const bf16x8_t*)&Bsl[br * 32 + ((lhi ^ ((br >> 1) & 3)) << 3)];
      }
      __builtin_amdgcn_s_setprio(1);
#pragma unroll
      for (int m = 0; m < 8; ++m)
#pragma unroll
        for (int n = 0; n < 4; ++n)
          acc[m][n] = __builtin_amdgcn_mfma_f32_16x16x32_bf16(af[m], bfr[n], acc[m][n], 0, 0, 0);
      __builtin_amdgcn_s_setprio(0);
    }
  }
}

// QKV GEMM. grid 384 = 32 by x 12 bx; XCD regions of 8 by x 6 bx (B slab 3 MB
// fits per-XCD L2). Blocks are purely Q (bx<4), K (4..7), or V (8..11).
// V-blocks write V^T via LDS transpose: C-tile -> SH[col][row^swz] -> 16
// coalesced b128 stores/thread (512B dense runs) instead of 8B/4KB scatter.
__global__ __launch_bounds__(512, 2) void k_gemm_qkv(
    const unsigned short* __restrict__ A, const unsigned short* __restrict__ Bt,
    const float* __restrict__ bias,
    unsigned short* __restrict__ Qo, unsigned short* __restrict__ Ko,
    unsigned short* __restrict__ Vo) {
  __shared__ alignas(16) unsigned short SH[65536];   // 128 KiB
  const int orig = blockIdx.x;
  const int xcd = orig & 7, lc = orig >> 3;          // 48 blocks per region
  const int by = (xcd >> 1) * 8 + lc / 6;
  const int bx = (xcd & 1) * 6 + lc % 6;
  f32x4_t acc[8][4];
  f32x4_t z = {0.f, 0.f, 0.f, 0.f};
#pragma unroll
  for (int m = 0; m < 8; ++m)
#pragma unroll
    for (int n = 0; n < 4; ++n) acc[m][n] = z;
  gemm_core(A, Bt, 1024, by * 256, bx * 256, SH, acc);
  const int tid = threadIdx.x, lane = tid & 63;
  const int wid = tid >> 6, wm = wid >> 2, wn = wid & 3;
  const int l15 = lane & 15, lhi = (lane >> 4) & 3;
  if (bx < 8) {
    // ---- Q / K: direct stores (32B dense per 16 lanes) ----
#pragma unroll
    for (int n = 0; n < 4; ++n) {
      int col = bx * 256 + wn * 64 + n * 16 + l15;
      int which = col >> 10;               // 0=q 1=k (block-uniform)
      int h = (col >> 6) & 15;
      int d = col & 63;
      float bv = bias[col];
      unsigned short* dst = which == 0 ? Qo : Ko;
      float scale = which == 0 ? 0.18033688011112042f : 1.0f;
#pragma unroll
      for (int m = 0; m < 8; ++m)
#pragma unroll
        for (int r = 0; r < 4; ++r) {
          int row = by * 256 + wm * 128 + m * 16 + lhi * 4 + r;
          int b = row >> 11, t = row & 2047;
          dst[(size_t)((b * 16 + h) * 2048 + t) * 64 + d] =
              f2bf((acc[m][n][r] + bv) * scale);
        }
    }
  } else {
    // ---- V: LDS transpose -> coalesced V^T stores ----
    __syncthreads();                       // all waves done with K-loop LDS
#pragma unroll
    for (int n = 0; n < 4; ++n) {
      const int col_l = wn * 64 + n * 16 + l15;
      const float bv = bias[bx * 256 + col_l];
      const int swz = (col_l & 3) << 3;    // XOR on row bits 3-4 (8-row units)
#pragma unroll
      for (int m = 0; m < 8; ++m) {
        const int row0 = wm * 128 + m * 16 + lhi * 4;
        u16x4_t pk;
#pragma unroll
        for (int r = 0; r < 4; ++r) pk[r] = f2bf(acc[m][n][r] + bv);
        *(u16x4_t*)&SH[col_l * 256 + (row0 ^ swz)] = pk;   // 8B, stays intact
      }
    }
    __syncthreads();
#pragma unroll
    for (int i = 0; i < 16; ++i) {
      const int flat = i * 512 + tid;
      const int col_l = flat >> 5;         // 0..255
      const int rg8 = flat & 31;           // 8-row chunk index
      bf16x8_t v = *(const bf16x8_t*)&SH[col_l * 256 + ((rg8 ^ (col_l & 3)) << 3)];
      const int vcol = bx * 256 + col_l - 2048;   // 0..1023
      const int h = vcol >> 6, d = vcol & 63;
      const int rg = by * 256 + rg8 * 8;
      const int b = rg >> 11, t = rg & 2047;
      *(bf16x8_t*)&Vo[((size_t)((b * 16 + h) * 64 + d)) * 2048 + t] = v;
    }
  }
}

// proj GEMM: out fp32 [8192][1024]. grid 128 = 32 by x 4 bx; regions 8x2.
__global__ __launch_bounds__(512, 2) void k_gemm_proj(
    const unsigned short* __restrict__ A, const unsigned short* __restrict__ Bt,
    const float* __restrict__ bias, float* __restrict__ out) {
  __shared__ alignas(16) unsigned short SH[65536];
  const int orig = blockIdx.x;
  const int xcd = orig & 7, lc = orig >> 3;          // 16 blocks per region
  const int by = (xcd >> 1) * 8 + (lc >> 1);
  const int bx = (xcd & 1) * 2 + (lc & 1);
  f32x4_t acc[8][4];
  f32x4_t z = {0.f, 0.f, 0.f, 0.f};
#pragma unroll
  for (int m = 0; m < 8; ++m)
#pragma unroll
    for (int n = 0; n < 4; ++n) acc[m][n] = z;
  gemm_core(A, Bt, 1024, by * 256, bx * 256, SH, acc);
  const int tid = threadIdx.x, lane = tid & 63;
  const int wid = tid >> 6, wm = wid >> 2, wn = wid & 3;
  const int l15 = lane & 15, lhi = (lane >> 4) & 3;
#pragma unroll
  for (int n = 0; n < 4; ++n) {
    int col = bx * 256 + wn * 64 + n * 16 + l15;
    float bv = bias[col];
#pragma unroll
    for (int m = 0; m < 8; ++m)
#pragma unroll
      for (int r = 0; r < 4; ++r) {
        int row = by * 256 + wm * 128 + m * 16 + lhi * 4 + r;
        out[(size_t)row * 1024 + col] = acc[m][n][r] + bv;
      }
  }
}

// ---------------------------------------------------------------------------
// causal flash attention, 32x32 swapped structure (T12) — unchanged.
__global__ __launch_bounds__(256) void k_attn(const unsigned short* __restrict__ Q,
                                              const unsigned short* __restrict__ K,
                                              const unsigned short* __restrict__ Vt,
                                              unsigned short* __restrict__ O) {
  __shared__ alignas(16) unsigned short KT[2][4096];  // [kv 64][d 64] swizzled
  __shared__ alignas(16) unsigned short VT[2][4096];  // [d 64][kv 64] swizzled
  const int flat = blockIdx.x;
  const int bx = 15 - (flat >> 6);       // heavy diagonal blocks first
  const int bh = flat & 63;              // same bh -> same XCD (64 % 8 == 0)
  const int tid = threadIdx.x;
  const int lane = tid & 63;
  const int w = tid >> 6;
  const int l31 = lane & 31;
  const int hi = lane >> 5;
  const int sw = l31 & 7;                // read-side XOR chunk (row&7)
  const unsigned short* Qh = Q + (size_t)bh * 2048 * 64;
  const unsigned short* Kh = K + (size_t)bh * 2048 * 64;
  const unsigned short* Vh = Vt + (size_t)bh * 64 * 2048;
  const int qrow = bx * 128 + w * 32;    // wave q-base
  const int qg = qrow + l31;             // lane's q row
  const int NT = 2 * bx + 2;             // kv tiles staged by this block

  bf16x8_t qf[4];
#pragma unroll
  for (int s = 0; s < 4; ++s)
    qf[s] = *(const bf16x8_t*)&Qh[(size_t)qg * 64 + s * 16 + hi * 8];

  f32x16_t ot0 = zero16(), ot1 = zero16();  // O^T: d-tiles 0/1, col=q=l31
  float m_r = -1e30f, l_r = 0.f;

  const int srow = tid >> 3;             // staging row 0..31 (+32 second half)
  const int ssw = 8 * ((tid & 7) ^ (srow & 7));  // source-side XOR (u16)
  auto STAGE = [&](int t_, int buf_) {
#pragma unroll
    for (int i = 0; i < 2; ++i) {
      const int r_ = i * 32 + srow;
      gload16(Kh + (size_t)(t_ * 64 + r_) * 64 + ssw, &KT[buf_][i * 2048 + tid * 8]);
      gload16(Vh + (size_t)r_ * 2048 + t_ * 64 + ssw, &VT[buf_][i * 2048 + tid * 8]);
    }
  };

  STAGE(0, 0);
  __syncthreads();
  for (int t = 0; t < NT; ++t) {
    const int buf = t & 1;
    if (t + 1 < NT) STAGE(t + 1, buf ^ 1);
    if (t * 64 <= qrow + 31) {           // wave-uniform: tile intersects causal range
      f32x16_t st[2];
#pragma unroll
      for (int tt = 0; tt < 2; ++tt) {
        st[tt] = zero16();
        const unsigned short* kr = &KT[buf][(tt * 32 + l31) * 64];
#pragma unroll
        for (int s = 0; s < 4; ++s) {
          bf16x8_t kf = *(const bf16x8_t*)&kr[((2 * s + hi) ^ sw) * 8];
          st[tt] = __builtin_amdgcn_mfma_f32_32x32x16_bf16(kf, qf[s], st[tt], 0, 0, 0);
        }
      }
      if (t * 64 + 63 > qrow) {
#pragma unroll
        for (int tt = 0; tt < 2; ++tt)
#pragma unroll
          for (int r = 0; r < 16; ++r) {
            int kv = t * 64 + tt * 32 + (r & 3) + 8 * (r >> 2) + 4 * hi;
            if (kv > qg) st[tt][r] = -1e30f;
          }
      }
      float mx = st[0][0];
#pragma unroll
      for (int tt = 0; tt < 2; ++tt)
#pragma unroll
        for (int r = 0; r < 16; ++r) mx = fmaxf(mx, st[tt][r]);
      mx = fmaxf(mx, __shfl_xor(mx, 32));
      float mnew = fmaxf(m_r, mx);
      float resc = __builtin_amdgcn_exp2f(m_r - mnew);
      float u = 0.f;
#pragma unroll
      for (int tt = 0; tt < 2; ++tt)
#pragma unroll
        for (int r = 0; r < 16; ++r) {
          float pv = __builtin_amdgcn_exp2f(st[tt][r] - mnew);
          st[tt][r] = pv;
          u += pv;
        }
      u += __shfl_xor(u, 32);
      l_r = l_r * resc + u;
      m_r = mnew;
      ot0 *= resc;
      ot1 *= resc;
#pragma unroll
      for (int tt = 0; tt < 2; ++tt) {
        unsigned W0 = cvt_pk_bf16(st[tt][0], st[tt][1]);
        unsigned W1 = cvt_pk_bf16(st[tt][2], st[tt][3]);
        unsigned W2 = cvt_pk_bf16(st[tt][4], st[tt][5]);
        unsigned W3 = cvt_pk_bf16(st[tt][6], st[tt][7]);
        unsigned W4 = cvt_pk_bf16(st[tt][8], st[tt][9]);
        unsigned W5 = cvt_pk_bf16(st[tt][10], st[tt][11]);
        unsigned W6 = cvt_pk_bf16(st[tt][12], st[tt][13]);
        unsigned W7 = cvt_pk_bf16(st[tt][14], st[tt][15]);
        perm32swap(W0, W2);
        perm32swap(W1, W3);
        perm32swap(W4, W6);
        perm32swap(W5, W7);
        u32x4_t fe = {W0, W1, W2, W3};   // kv window 32tt + [0,16)
        u32x4_t fo = {W4, W5, W6, W7};   // kv window 32tt + [16,32)
        bf16x8_t pe = __builtin_bit_cast(bf16x8_t, fe);
        bf16x8_t po = __builtin_bit_cast(bf16x8_t, fo);
        const unsigned short* vr0 = &VT[buf][l31 * 64];         // d-tile 0
        const unsigned short* vr1 = &VT[buf][(32 + l31) * 64];  // d-tile 1
        bf16x8_t ve0 = *(const bf16x8_t*)&vr0[((4 * tt + hi) ^ sw) * 8];
        bf16x8_t vo0 = *(const bf16x8_t*)&vr0[((4 * tt + 2 + hi) ^ sw) * 8];
        bf16x8_t ve1 = *(const bf16x8_t*)&vr1[((4 * tt + hi) ^ sw) * 8];
        bf16x8_t vo1 = *(const bf16x8_t*)&vr1[((4 * tt + 2 + hi) ^ sw) * 8];
        ot0 = __builtin_amdgcn_mfma_f32_32x32x16_bf16(ve0, pe, ot0, 0, 0, 0);
        ot0 = __builtin_amdgcn_mfma_f32_32x32x16_bf16(vo0, po, ot0, 0, 0, 0);
        ot1 = __builtin_amdgcn_mfma_f32_32x32x16_bf16(ve1, pe, ot1, 0, 0, 0);
        ot1 = __builtin_amdgcn_mfma_f32_32x32x16_bf16(vo1, po, ot1, 0, 0, 0);
      }
    }
    __syncthreads();
  }
  const float inv = 1.0f / l_r;
  const int b = bh >> 4, h = bh & 15;
  unsigned short* orow = O + (size_t)(b * 2048 + qg) * 1024 + h * 64;
#pragma unroll
  for (int m = 0; m < 4; ++m) {          // d = 8m + 4hi + {0..3} (+32 for ot1)
    u16x4_t r0, r1;
#pragma unroll
    for (int j = 0; j < 4; ++j) {
      r0[j] = f2bf(ot0[4 * m + j] * inv);
      r1[j] = f2bf(ot1[4 * m + j] * inv);
    }
    *(u16x4_t*)&orow[8 * m + 4 * hi] = r0;
    *(u16x4_t*)&orow[32 + 8 * m + 4 * hi] = r1;
  }
}

// ---------------------------------------------------------------------------
extern "C" void kernel_launch(void* const* d_in, const int* in_sizes, int n_in,
                              void* d_out, int out_size, void* d_ws, size_t ws_size,
                              hipStream_t stream) {
  const float* x     = (const float*)d_in[0];
  const float* Wqkv  = (const float*)d_in[1];
  const float* bqkv  = (const float*)d_in[2];
  const float* Wproj = (const float*)d_in[3];
  const float* bproj = (const float*)d_in[4];
  float* out = (float*)d_out;

  char* ws = (char*)d_ws;
  unsigned short* xb     = (unsigned short*)(ws);                    // 16 MiB
  unsigned short* wqkvT  = (unsigned short*)(ws + 16777216);         // 6 MiB
  unsigned short* wprojT = (unsigned short*)(ws + 23068672);         // 2 MiB
  unsigned short* Qb     = (unsigned short*)(ws + 25165824);         // 16 MiB (B,H,T,D) *0.125*log2e
  unsigned short* Kb     = (unsigned short*)(ws + 41943040);         // 16 MiB (B,H,T,D)
  unsigned short* Vb     = (unsigned short*)(ws + 58720256);         // 16 MiB (B,H,D,T) transposed
  unsigned short* Ob     = (unsigned short*)(ws + 75497472);         // 16 MiB (B,T,C)

  k_cast_bf16<<<8192, 256, 0, stream>>>(x, xb);
  k_transpose_cast<<<dim3(96, 32), dim3(32, 8), 0, stream>>>(Wqkv, wqkvT, 1024, 3072);
  k_transpose_cast<<<dim3(32, 32), dim3(32, 8), 0, stream>>>(Wproj, wprojT, 1024, 1024);
  k_gemm_qkv<<<384, 512, 0, stream>>>(xb, wqkvT, bqkv, Qb, Kb, Vb);
  k_attn<<<1024, 256, 0, stream>>>(Qb, Kb, Vb, Ob);
  k_gemm_proj<<<128, 512, 0, stream>>>(Ob, wprojT, bproj, out);
}

// Round 12
// 248.599 us; speedup vs baseline: 1.1702x; 1.0367x over previous
//
#include <hip/hip_runtime.h>
#include <stdint.h>

// ---------------------------------------------------------------------------
// CausalSelfAttention (B=4, T=2048, C=1024, H=16, D=64) on gfx950.
// cast x->bf16; transpose W's to [N][K] bf16; QKV GEMM (256x256 tile, 8-wave,
// k-half-phased counted-vmcnt schedule, swizzled LDS, V^T via LDS transpose,
// line-merged Q/K stores, 2D XCD-region swizzle); causal flash attention
// (32x32 swapped-QK^T); proj GEMM (same core, BM=128, full-GPU grid).
// ---------------------------------------------------------------------------

typedef __attribute__((ext_vector_type(8))) __bf16 bf16x8_t;   // MFMA A/B frag
typedef __attribute__((ext_vector_type(4))) float f32x4_t;     // 16x16 C/D
typedef __attribute__((ext_vector_type(16))) float f32x16_t;   // 32x32 C/D
typedef __attribute__((ext_vector_type(4))) unsigned short u16x4_t;
typedef __attribute__((ext_vector_type(4))) unsigned int u32x4_t;

static __device__ __forceinline__ unsigned short f2bf(float f) {
  union { float f; unsigned u; } c; c.f = f;
  unsigned r = c.u + 0x7FFFu + ((c.u >> 16) & 1u);  // RNE
  return (unsigned short)(r >> 16);
}

static __device__ __forceinline__ unsigned cvt_pk_bf16(float lo, float hi) {
  unsigned r;
  asm volatile("v_cvt_pk_bf16_f32 %0, %1, %2" : "=v"(r) : "v"(lo), "v"(hi));
  return r;
}

// v_permlane32_swap_b32 a,b : a.hi32lanes <-> b.lo32lanes (both updated)
static __device__ __forceinline__ void perm32swap(unsigned& a, unsigned& b) {
  asm volatile("v_permlane32_swap_b32 %0, %1" : "+v"(a), "+v"(b));
}

static __device__ __forceinline__ f32x16_t zero16() {
  f32x16_t v;
#pragma unroll
  for (int i = 0; i < 16; ++i) v[i] = 0.f;
  return v;
}

// async global->LDS, 16B per lane. LDS dest must be (wave-uniform base +
// lane*16) linear; global src IS per-lane (m173) -> swizzle the source.
static __device__ __forceinline__ void gload16(const void* g, void* lds) {
  __builtin_amdgcn_global_load_lds(
      (const __attribute__((address_space(1))) unsigned int*)g,
      (__attribute__((address_space(3))) unsigned int*)(uint32_t)(uintptr_t)lds,
      16, 0, 0);
}

// ---------------------------------------------------------------------------
__global__ __launch_bounds__(256) void k_cast_bf16(const float* __restrict__ in,
                                                   unsigned short* __restrict__ out) {
  int i = blockIdx.x * 256 + threadIdx.x;
  float4 v = ((const float4*)in)[i];
  u16x4_t r = { f2bf(v.x), f2bf(v.y), f2bf(v.z), f2bf(v.w) };
  ((u16x4_t*)out)[i] = r;
}

__global__ __launch_bounds__(256) void k_transpose_cast(const float* __restrict__ W,
                                                        unsigned short* __restrict__ Wt,
                                                        int Kd, int Nd) {
  __shared__ float tile[32][33];
  int n0 = blockIdx.x * 32, k0 = blockIdx.y * 32;
  int tx = threadIdx.x, ty = threadIdx.y;
#pragma unroll
  for (int i = 0; i < 4; ++i)
    tile[ty + 8 * i][tx] = W[(size_t)(k0 + ty + 8 * i) * Nd + n0 + tx];
  __syncthreads();
#pragma unroll
  for (int i = 0; i < 4; ++i)
    Wt[(size_t)(n0 + ty + 8 * i) * Kd + k0 + tx] = f2bf(tile[tx][ty + 8 * i]);
}

// ---------------------------------------------------------------------------
// Phased GEMM core, templated on per-wave M-frags MW (8 -> BM=256; 4 -> BM=128).
// BN=256 fixed, BK=64 in 2 k-half phases, 8 waves (2m x 4n), per-wave C =
// (MW*16) x 64. LDS from SH: A halves at s*(MW*1024) u16, B at MW*4096 +
// s*8192 u16 (s = slot*2+half). In-half swizzle chunk^=(row>>1)&3 (involution,
// source+read sides, gload dest linear). Phase: vmcnt(MW/4+2) -> barrier ->
// STAGE(next tile half -> slot^1) -> ds_reads -> setprio(1) MFMA setprio(0).
// Gate derivation: 2 STAGEs (each MW/4+2 loads) in flight at gate; retiring to
// MW/4+2 confirms the oldest = the half about to be read. Tail clamp re-stages
// a dead slot keeping counts uniform.
template <int MW>
static __device__ __forceinline__ void gemm_core(
    const unsigned short* __restrict__ A, const unsigned short* __restrict__ Bt,
    int Kd, int bm0, int bn0, unsigned short* SH, f32x4_t (*acc)[4]) {
  const int tid = threadIdx.x;
  const int lane = tid & 63;
  const int wid = tid >> 6;
  const int wm = wid >> 2, wn = wid & 3;
  const int l15 = lane & 15, lhi = (lane >> 4) & 3;
  const int r0 = tid >> 2;                 // staging row 0..127
  const int cd = tid & 3;                  // staging dest chunk
  const int NK = Kd >> 6;

  auto STAGE = [&](int kt, int h, int sl) {
    unsigned short* Asl = SH + (sl * 2 + h) * (MW * 1024);
    unsigned short* Bsl = SH + MW * 4096 + (sl * 2 + h) * 8192;
#pragma unroll
    for (int j = 0; j < MW / 4; ++j) {
      const int row = r0 + 128 * j;
      const int sc = cd ^ ((row >> 1) & 3);          // source chunk (inverse swz)
      gload16(A + (size_t)(bm0 + row) * Kd + kt * 64 + h * 32 + sc * 8,
              &Asl[row * 32 + cd * 8]);
    }
#pragma unroll
    for (int j = 0; j < 2; ++j) {
      const int row = r0 + 128 * j;
      const int sc = cd ^ ((row >> 1) & 3);
      gload16(Bt + (size_t)(bn0 + row) * Kd + kt * 64 + h * 32 + sc * 8,
              &Bsl[row * 32 + cd * 8]);
    }
  };

  STAGE(0, 0, 0);
  STAGE(0, 1, 0);
  for (int kt = 0; kt < NK; ++kt) {
    const int sl = kt & 1;
    const int ktn = (kt + 1 < NK) ? kt + 1 : kt;     // tail clamp (dead slot)
#pragma unroll
    for (int h = 0; h < 2; ++h) {
      if constexpr (MW == 8)
        asm volatile("s_waitcnt vmcnt(4)" ::: "memory");
      else
        asm volatile("s_waitcnt vmcnt(3)" ::: "memory");
      __builtin_amdgcn_sched_barrier(0);
      __builtin_amdgcn_s_barrier();
      __builtin_amdgcn_sched_barrier(0);
      STAGE(ktn, h, sl ^ 1);
      const unsigned short* Asl = SH + (sl * 2 + h) * (MW * 1024);
      const unsigned short* Bsl = SH + MW * 4096 + (sl * 2 + h) * 8192;
      bf16x8_t af[MW], bfr[4];
#pragma unroll
      for (int m = 0; m < MW; ++m) {
        const int ar = wm * (MW * 16) + m * 16 + l15;
        af[m] = *(const bf16x8_t*)&Asl[ar * 32 + ((lhi ^ ((ar >> 1) & 3)) << 3)];
      }
#pragma unroll
      for (int n = 0; n < 4; ++n) {
        const int br = wn * 64 + n * 16 + l15;
        bfr[n] = *(const bf16x8_t*)&Bsl[br * 32 + ((lhi ^ ((br >> 1) & 3)) << 3)];
      }
      __builtin_amdgcn_s_setprio(1);
#pragma unroll
      for (int m = 0; m < MW; ++m)
#pragma unroll
        for (int n = 0; n < 4; ++n)
          acc[m][n] = __builtin_amdgcn_mfma_f32_16x16x32_bf16(af[m], bfr[n], acc[m][n], 0, 0, 0);
      __builtin_amdgcn_s_setprio(0);
    }
  }
}

// QKV GEMM. grid 384 = 32 by x 12 bx; XCD regions of 8 by x 6 bx. Blocks are
// purely Q (bx<4), K (4..7), or V (8..11). Q/K: line-merged direct stores
// (4 same-128B-line segments issued back-to-back). V: LDS transpose -> dense
// b128 stores of V^T.
__global__ __launch_bounds__(512, 2) void k_gemm_qkv(
    const unsigned short* __restrict__ A, const unsigned short* __restrict__ Bt,
    const float* __restrict__ bias,
    unsigned short* __restrict__ Qo, unsigned short* __restrict__ Ko,
    unsigned short* __restrict__ Vo) {
  __shared__ alignas(16) unsigned short SH[65536];   // 128 KiB
  const int orig = blockIdx.x;
  const int xcd = orig & 7, lc = orig >> 3;          // 48 blocks per region
  const int by = (xcd >> 1) * 8 + lc / 6;
  const int bx = (xcd & 1) * 6 + lc % 6;
  f32x4_t acc[8][4];
  f32x4_t z = {0.f, 0.f, 0.f, 0.f};
#pragma unroll
  for (int m = 0; m < 8; ++m)
#pragma unroll
    for (int n = 0; n < 4; ++n) acc[m][n] = z;
  gemm_core<8>(A, Bt, 1024, by * 256, bx * 256, SH, acc);
  const int tid = threadIdx.x, lane = tid & 63;
  const int wid = tid >> 6, wm = wid >> 2, wn = wid & 3;
  const int l15 = lane & 15, lhi = (lane >> 4) & 3;
  if (bx < 8) {
    // ---- Q / K: direct stores, n innermost so 4 segments of each 128B
    // d-line issue consecutively and merge in L2 ----
    const int col0 = bx * 256 + wn * 64;   // head-aligned
    const int which = col0 >> 10;          // 0=q 1=k (block-uniform)
    const int h = (col0 >> 6) & 15;
    unsigned short* dst = which == 0 ? Qo : Ko;
    const float scale = which == 0 ? 0.18033688011112042f : 1.0f;
    float bv[4];
#pragma unroll
    for (int n = 0; n < 4; ++n) bv[n] = bias[col0 + n * 16 + l15];
#pragma unroll
    for (int m = 0; m < 8; ++m)
#pragma unroll
      for (int r = 0; r < 4; ++r) {
        const int row = by * 256 + wm * 128 + m * 16 + lhi * 4 + r;
        const int b = row >> 11, t = row & 2047;
        const size_t base = (size_t)((b * 16 + h) * 2048 + t) * 64 + l15;
#pragma unroll
        for (int n = 0; n < 4; ++n)
          dst[base + n * 16] = f2bf((acc[m][n][r] + bv[n]) * scale);
      }
  } else {
    // ---- V: LDS transpose -> coalesced V^T stores ----
    __syncthreads();                       // all waves done with K-loop LDS
#pragma unroll
    for (int n = 0; n < 4; ++n) {
      const int col_l = wn * 64 + n * 16 + l15;
      const float bv = bias[bx * 256 + col_l];
      const int swz = (col_l & 3) << 3;    // XOR on 8-row granules
#pragma unroll
      for (int m = 0; m < 8; ++m) {
        const int row0 = wm * 128 + m * 16 + lhi * 4;
        u16x4_t pk;
#pragma unroll
        for (int r = 0; r < 4; ++r) pk[r] = f2bf(acc[m][n][r] + bv);
        *(u16x4_t*)&SH[col_l * 256 + (row0 ^ swz)] = pk;   // 8B, stays intact
      }
    }
    __syncthreads();
#pragma unroll
    for (int i = 0; i < 16; ++i) {
      const int flat = i * 512 + tid;
      const int col_l = flat >> 5;         // 0..255
      const int rg8 = flat & 31;           // 8-row chunk index
      bf16x8_t v = *(const bf16x8_t*)&SH[col_l * 256 + ((rg8 ^ (col_l & 3)) << 3)];
      const int vcol = bx * 256 + col_l - 2048;   // 0..1023
      const int h = vcol >> 6, d = vcol & 63;
      const int rg = by * 256 + rg8 * 8;
      const int b = rg >> 11, t = rg & 2047;
      *(bf16x8_t*)&Vo[((size_t)((b * 16 + h) * 64 + d)) * 2048 + t] = v;
    }
  }
}

// proj GEMM: out fp32 [8192][1024]. BM=128 (MW=4): grid 256 = 64 by x 4 bx =
// exactly one full-GPU round (was 128 blocks = half idle). Regions 8 by x 4 bx.
__global__ __launch_bounds__(512, 2) void k_gemm_proj(
    const unsigned short* __restrict__ A, const unsigned short* __restrict__ Bt,
    const float* __restrict__ bias, float* __restrict__ out) {
  __shared__ alignas(16) unsigned short SH[49152];   // 96 KiB (MW=4)
  const int orig = blockIdx.x;
  const int xcd = orig & 7, lc = orig >> 3;          // 32 blocks per region
  const int by = xcd * 8 + (lc >> 2);
  const int bx = lc & 3;
  f32x4_t acc[4][4];
  f32x4_t z = {0.f, 0.f, 0.f, 0.f};
#pragma unroll
  for (int m = 0; m < 4; ++m)
#pragma unroll
    for (int n = 0; n < 4; ++n) acc[m][n] = z;
  gemm_core<4>(A, Bt, 1024, by * 128, bx * 256, SH, acc);
  const int tid = threadIdx.x, lane = tid & 63;
  const int wid = tid >> 6, wm = wid >> 2, wn = wid & 3;
  const int l15 = lane & 15, lhi = (lane >> 4) & 3;
#pragma unroll
  for (int n = 0; n < 4; ++n) {
    int col = bx * 256 + wn * 64 + n * 16 + l15;
    float bv = bias[col];
#pragma unroll
    for (int m = 0; m < 4; ++m)
#pragma unroll
      for (int r = 0; r < 4; ++r) {
        int row = by * 128 + wm * 64 + m * 16 + lhi * 4 + r;
        out[(size_t)row * 1024 + col] = acc[m][n][r] + bv;
      }
  }
}

// ---------------------------------------------------------------------------
// causal flash attention, 32x32 swapped structure (T12) — unchanged.
__global__ __launch_bounds__(256) void k_attn(const unsigned short* __restrict__ Q,
                                              const unsigned short* __restrict__ K,
                                              const unsigned short* __restrict__ Vt,
                                              unsigned short* __restrict__ O) {
  __shared__ alignas(16) unsigned short KT[2][4096];  // [kv 64][d 64] swizzled
  __shared__ alignas(16) unsigned short VT[2][4096];  // [d 64][kv 64] swizzled
  const int flat = blockIdx.x;
  const int bx = 15 - (flat >> 6);       // heavy diagonal blocks first
  const int bh = flat & 63;              // same bh -> same XCD (64 % 8 == 0)
  const int tid = threadIdx.x;
  const int lane = tid & 63;
  const int w = tid >> 6;
  const int l31 = lane & 31;
  const int hi = lane >> 5;
  const int sw = l31 & 7;                // read-side XOR chunk (row&7)
  const unsigned short* Qh = Q + (size_t)bh * 2048 * 64;
  const unsigned short* Kh = K + (size_t)bh * 2048 * 64;
  const unsigned short* Vh = Vt + (size_t)bh * 64 * 2048;
  const int qrow = bx * 128 + w * 32;    // wave q-base
  const int qg = qrow + l31;             // lane's q row
  const int NT = 2 * bx + 2;             // kv tiles staged by this block

  bf16x8_t qf[4];
#pragma unroll
  for (int s = 0; s < 4; ++s)
    qf[s] = *(const bf16x8_t*)&Qh[(size_t)qg * 64 + s * 16 + hi * 8];

  f32x16_t ot0 = zero16(), ot1 = zero16();  // O^T: d-tiles 0/1, col=q=l31
  float m_r = -1e30f, l_r = 0.f;

  const int srow = tid >> 3;             // staging row 0..31 (+32 second half)
  const int ssw = 8 * ((tid & 7) ^ (srow & 7));  // source-side XOR (u16)
  auto STAGE = [&](int t_, int buf_) {
#pragma unroll
    for (int i = 0; i < 2; ++i) {
      const int r_ = i * 32 + srow;
      gload16(Kh + (size_t)(t_ * 64 + r_) * 64 + ssw, &KT[buf_][i * 2048 + tid * 8]);
      gload16(Vh + (size_t)r_ * 2048 + t_ * 64 + ssw, &VT[buf_][i * 2048 + tid * 8]);
    }
  };

  STAGE(0, 0);
  __syncthreads();
  for (int t = 0; t < NT; ++t) {
    const int buf = t & 1;
    if (t + 1 < NT) STAGE(t + 1, buf ^ 1);
    if (t * 64 <= qrow + 31) {           // wave-uniform: tile intersects causal range
      f32x16_t st[2];
#pragma unroll
      for (int tt = 0; tt < 2; ++tt) {
        st[tt] = zero16();
        const unsigned short* kr = &KT[buf][(tt * 32 + l31) * 64];
#pragma unroll
        for (int s = 0; s < 4; ++s) {
          bf16x8_t kf = *(const bf16x8_t*)&kr[((2 * s + hi) ^ sw) * 8];
          st[tt] = __builtin_amdgcn_mfma_f32_32x32x16_bf16(kf, qf[s], st[tt], 0, 0, 0);
        }
      }
      if (t * 64 + 63 > qrow) {
#pragma unroll
        for (int tt = 0; tt < 2; ++tt)
#pragma unroll
          for (int r = 0; r < 16; ++r) {
            int kv = t * 64 + tt * 32 + (r & 3) + 8 * (r >> 2) + 4 * hi;
            if (kv > qg) st[tt][r] = -1e30f;
          }
      }
      float mx = st[0][0];
#pragma unroll
      for (int tt = 0; tt < 2; ++tt)
#pragma unroll
        for (int r = 0; r < 16; ++r) mx = fmaxf(mx, st[tt][r]);
      mx = fmaxf(mx, __shfl_xor(mx, 32));
      float mnew = fmaxf(m_r, mx);
      float resc = __builtin_amdgcn_exp2f(m_r - mnew);
      float u = 0.f;
#pragma unroll
      for (int tt = 0; tt < 2; ++tt)
#pragma unroll
        for (int r = 0; r < 16; ++r) {
          float pv = __builtin_amdgcn_exp2f(st[tt][r] - mnew);
          st[tt][r] = pv;
          u += pv;
        }
      u += __shfl_xor(u, 32);
      l_r = l_r * resc + u;
      m_r = mnew;
      ot0 *= resc;
      ot1 *= resc;
#pragma unroll
      for (int tt = 0; tt < 2; ++tt) {
        unsigned W0 = cvt_pk_bf16(st[tt][0], st[tt][1]);
        unsigned W1 = cvt_pk_bf16(st[tt][2], st[tt][3]);
        unsigned W2 = cvt_pk_bf16(st[tt][4], st[tt][5]);
        unsigned W3 = cvt_pk_bf16(st[tt][6], st[tt][7]);
        unsigned W4 = cvt_pk_bf16(st[tt][8], st[tt][9]);
        unsigned W5 = cvt_pk_bf16(st[tt][10], st[tt][11]);
        unsigned W6 = cvt_pk_bf16(st[tt][12], st[tt][13]);
        unsigned W7 = cvt_pk_bf16(st[tt][14], st[tt][15]);
        perm32swap(W0, W2);
        perm32swap(W1, W3);
        perm32swap(W4, W6);
        perm32swap(W5, W7);
        u32x4_t fe = {W0, W1, W2, W3};   // kv window 32tt + [0,16)
        u32x4_t fo = {W4, W5, W6, W7};   // kv window 32tt + [16,32)
        bf16x8_t pe = __builtin_bit_cast(bf16x8_t, fe);
        bf16x8_t po = __builtin_bit_cast(bf16x8_t, fo);
        const unsigned short* vr0 = &VT[buf][l31 * 64];         // d-tile 0
        const unsigned short* vr1 = &VT[buf][(32 + l31) * 64];  // d-tile 1
        bf16x8_t ve0 = *(const bf16x8_t*)&vr0[((4 * tt + hi) ^ sw) * 8];
        bf16x8_t vo0 = *(const bf16x8_t*)&vr0[((4 * tt + 2 + hi) ^ sw) * 8];
        bf16x8_t ve1 = *(const bf16x8_t*)&vr1[((4 * tt + hi) ^ sw) * 8];
        bf16x8_t vo1 = *(const bf16x8_t*)&vr1[((4 * tt + 2 + hi) ^ sw) * 8];
        ot0 = __builtin_amdgcn_mfma_f32_32x32x16_bf16(ve0, pe, ot0, 0, 0, 0);
        ot0 = __builtin_amdgcn_mfma_f32_32x32x16_bf16(vo0, po, ot0, 0, 0, 0);
        ot1 = __builtin_amdgcn_mfma_f32_32x32x16_bf16(ve1, pe, ot1, 0, 0, 0);
        ot1 = __builtin_amdgcn_mfma_f32_32x32x16_bf16(vo1, po, ot1, 0, 0, 0);
      }
    }
    __syncthreads();
  }
  const float inv = 1.0f / l_r;
  const int b = bh >> 4, h = bh & 15;
  unsigned short* orow = O + (size_t)(b * 2048 + qg) * 1024 + h * 64;
#pragma unroll
  for (int m = 0; m < 4; ++m) {          // d = 8m + 4hi + {0..3} (+32 for ot1)
    u16x4_t r0, r1;
#pragma unroll
    for (int j = 0; j < 4; ++j) {
      r0[j] = f2bf(ot0[4 * m + j] * inv);
      r1[j] = f2bf(ot1[4 * m + j] * inv);
    }
    *(u16x4_t*)&orow[8 * m + 4 * hi] = r0;
    *(u16x4_t*)&orow[32 + 8 * m + 4 * hi] = r1;
  }
}

// ---------------------------------------------------------------------------
extern "C" void kernel_launch(void* const* d_in, const int* in_sizes, int n_in,
                              void* d_out, int out_size, void* d_ws, size_t ws_size,
                              hipStream_t stream) {
  const float* x     = (const float*)d_in[0];
  const float* Wqkv  = (const float*)d_in[1];
  const float* bqkv  = (const float*)d_in[2];
  const float* Wproj = (const float*)d_in[3];
  const float* bproj = (const float*)d_in[4];
  float* out = (float*)d_out;

  char* ws = (char*)d_ws;
  unsigned short* xb     = (unsigned short*)(ws);                    // 16 MiB
  unsigned short* wqkvT  = (unsigned short*)(ws + 16777216);         // 6 MiB
  unsigned short* wprojT = (unsigned short*)(ws + 23068672);         // 2 MiB
  unsigned short* Qb     = (unsigned short*)(ws + 25165824);         // 16 MiB (B,H,T,D) *0.125*log2e
  unsigned short* Kb     = (unsigned short*)(ws + 41943040);         // 16 MiB (B,H,T,D)
  unsigned short* Vb     = (unsigned short*)(ws + 58720256);         // 16 MiB (B,H,D,T) transposed
  unsigned short* Ob     = (unsigned short*)(ws + 75497472);         // 16 MiB (B,T,C)

  k_cast_bf16<<<8192, 256, 0, stream>>>(x, xb);
  k_transpose_cast<<<dim3(96, 32), dim3(32, 8), 0, stream>>>(Wqkv, wqkvT, 1024, 3072);
  k_transpose_cast<<<dim3(32, 32), dim3(32, 8), 0, stream>>>(Wproj, wprojT, 1024, 1024);
  k_gemm_qkv<<<384, 512, 0, stream>>>(xb, wqkvT, bqkv, Qb, Kb, Vb);
  k_attn<<<1024, 256, 0, stream>>>(Qb, Kb, Vb, Ob);
  k_gemm_proj<<<256, 512, 0, stream>>>(Ob, wprojT, bproj, out);
}